// Round 1
// baseline (45.750 us; speedup 1.0000x reference)
//
#include <hip/hip_runtime.h>
#include <math.h>

#define T_LEN 16384
#define B_ROWS 256
#define SEG 4                 // segments per row
#define EPT 16                // elements per thread
#define BLK 256

__device__ __forceinline__ float sigf(float x) {
    float e = expf(-fabsf(x));
    return (x >= 0.f) ? 1.0f / (1.0f + e) : e / (1.0f + e);
}

__global__ __launch_bounds__(256) void loss_partial(
    const float* __restrict__ pon, const float* __restrict__ poff,
    const float* __restrict__ ton, const float* __restrict__ toff,
    float* __restrict__ ws)
{
    const int T = T_LEN;
    int blk = blockIdx.x;
    int row = blk >> 2;          // SEG=4
    int s   = blk & 3;
    int tid = threadIdx.x;
    int c0  = s * (T / SEG) + tid * EPT;     // row-local chunk start
    size_t base = (size_t)row * T + c0;

    float on_pos = 0.f, on_neg = 0.f, on_cnt = 0.f;
    float off_pos = 0.f, off_neg = 0.f, off_cnt = 0.f;
    float on_psum = 0.f, off_psum = 0.f, cons = 0.f;
    float w0 = 0.f, w1 = 0.f, w2 = 0.f;      // rolling window of last 3 onset probs

    const float4* pon4  = (const float4*)(pon  + base);
    const float4* poff4 = (const float4*)(poff + base);
    const float4* ton4  = (const float4*)(ton  + base);
    const float4* toff4 = (const float4*)(toff + base);

    #pragma unroll
    for (int k = 0; k < EPT / 4; k++) {
        float4 xo = pon4[k], xf = poff4[k], to = ton4[k], tf = toff4[k];
        float xs[4] = {xo.x, xo.y, xo.z, xo.w};
        float fs[4] = {xf.x, xf.y, xf.z, xf.w};
        float ts[4] = {to.x, to.y, to.z, to.w};
        float us[4] = {tf.x, tf.y, tf.z, tf.w};
        #pragma unroll
        for (int j = 0; j < 4; j++) {
            int i = 4 * k + j;
            // ---- onset BCE + prob ----
            float x  = xs[j];
            float e  = expf(-fabsf(x));
            float sp = fmaxf(x, 0.f) + log1pf(e);     // softplus(x)
            float l  = sp - x * ts[j];
            if (ts[j] == 1.0f) { on_pos += fminf(l, 5.0f); on_cnt += 1.0f; }
            else               { on_neg += l; }
            float pr = (x >= 0.f) ? 1.0f / (1.0f + e) : e / (1.0f + e);
            on_psum += pr;
            // ---- offset BCE + prob ----
            float y   = fs[j];
            float e2  = expf(-fabsf(y));
            float sp2 = fmaxf(y, 0.f) + log1pf(e2);
            float l2  = sp2 - y * us[j];
            if (us[j] == 1.0f) { off_pos += fminf(l2, 5.0f); off_cnt += 1.0f; }
            else               { off_neg += l2; }
            float qr = (y >= 0.f) ? 1.0f / (1.0f + e2) : e2 / (1.0f + e2);
            off_psum += qr;
            // ---- consistency: violation index jg = c0+i-3, uses on[jg..jg+2], off[jg+3]=qr
            if (i >= 3) {
                float r = fmaxf(fmaxf(w0, w1), w2);
                if (r > 0.5f && qr > 0.5f) cons += r * qr;
            }
            w0 = w1; w1 = w2; w2 = pr;
        }
    }

    // ---- tail violations: jg = c0+13, c0+14, c0+15 (cross-chunk reads) ----
    {
        const float* onrow  = pon  + (size_t)row * T;
        const float* offrow = poff + (size_t)row * T;
        float e0 = 0.f, e1 = 0.f;
        if (c0 + 13 <= T - 4) {
            float f0 = sigf(offrow[c0 + 16]);
            float r = fmaxf(fmaxf(w0, w1), w2);
            if (r > 0.5f && f0 > 0.5f) cons += r * f0;
        }
        if (c0 + 14 <= T - 4) {
            e0 = sigf(onrow[c0 + 16]);
            float f1 = sigf(offrow[c0 + 17]);
            float r = fmaxf(fmaxf(w1, w2), e0);
            if (r > 0.5f && f1 > 0.5f) cons += r * f1;
        }
        if (c0 + 15 <= T - 4) {
            e1 = sigf(onrow[c0 + 17]);
            float f2 = sigf(offrow[c0 + 18]);
            float r = fmaxf(fmaxf(w2, e0), e1);
            if (r > 0.5f && f2 > 0.5f) cons += r * f2;
        }
    }

    // ---- block reduction: 9 partials ----
    float vals[9] = {on_pos, on_neg, on_cnt, off_pos, off_neg, off_cnt,
                     on_psum, off_psum, cons};
    #pragma unroll
    for (int v = 0; v < 9; v++) {
        float a = vals[v];
        for (int o = 32; o > 0; o >>= 1) a += __shfl_down(a, o, 64);
        vals[v] = a;
    }
    __shared__ float part[4][9];
    int lane = tid & 63, wid = tid >> 6;
    if (lane == 0) {
        #pragma unroll
        for (int v = 0; v < 9; v++) part[wid][v] = vals[v];
    }
    __syncthreads();
    if (tid == 0) {
        float* o = ws + (size_t)blk * 9;
        #pragma unroll
        for (int v = 0; v < 9; v++)
            o[v] = part[0][v] + part[1][v] + part[2][v] + part[3][v];
    }
}

__global__ __launch_bounds__(256) void finalize_k(const float* __restrict__ ws,
                                                  float* __restrict__ out)
{
    int r = threadIdx.x;   // one row per thread
    double a[9];
    #pragma unroll
    for (int v = 0; v < 9; v++) a[v] = 0.0;
    for (int s = 0; s < SEG; s++) {
        const float* p = ws + ((size_t)r * SEG + s) * 9;
        #pragma unroll
        for (int v = 0; v < 9; v++) a[v] += (double)p[v];
    }
    // red: 0..5 BCE partials, 6 onset prob total, 7 cons total, 8 per-row |pairing|
    double red[9];
    red[0] = a[0]; red[1] = a[1]; red[2] = a[2];
    red[3] = a[3]; red[4] = a[4]; red[5] = a[5];
    red[6] = a[6];
    red[7] = a[8];
    red[8] = fabs(a[6] - a[7]);
    #pragma unroll
    for (int v = 0; v < 9; v++) {
        double x = red[v];
        for (int o = 32; o > 0; o >>= 1) x += __shfl_down(x, o, 64);
        red[v] = x;
    }
    __shared__ double part[4][9];
    int lane = r & 63, wid = r >> 6;
    if (lane == 0) {
        #pragma unroll
        for (int v = 0; v < 9; v++) part[wid][v] = red[v];
    }
    __syncthreads();
    if (r == 0) {
        double t[9];
        #pragma unroll
        for (int v = 0; v < 9; v++)
            t[v] = part[0][v] + part[1][v] + part[2][v] + part[3][v];
        const double N = (double)B_ROWS * (double)T_LEN;
        double pc = t[2], nc = N - pc;
        double pl = (pc > 0) ? t[0] / fmax(pc, 1.0) : 0.0;
        double nl = (nc > 0) ? t[1] / fmax(nc, 1.0) : 0.0;
        double onset_loss = 1.5 * pl + nl;
        double pc2 = t[5], nc2 = N - pc2;
        double pl2 = (pc2 > 0) ? t[3] / fmax(pc2, 1.0) : 0.0;
        double nl2 = (nc2 > 0) ? t[4] / fmax(nc2, 1.0) : 0.0;
        double offset_loss = 1.5 * pl2 + nl2;
        double cons_loss = t[7] / ((double)B_ROWS * (double)(T_LEN - 3));
        double pair_loss = t[8] / (double)B_ROWS;
        double mean_on   = t[6] / N;
        double sparsity  = 0.0;   // SPARSE_W == 0
        double total = 5.0 * onset_loss + 3.0 * offset_loss + 0.1 * cons_loss
                     + 0.05 * pair_loss + sparsity;
        out[0] = (float)onset_loss;
        out[1] = (float)offset_loss;
        out[2] = (float)cons_loss;
        out[3] = (float)pair_loss;
        out[4] = (float)sparsity;
        out[5] = (float)mean_on;
        out[6] = (float)total;
    }
}

extern "C" void kernel_launch(void* const* d_in, const int* in_sizes, int n_in,
                              void* d_out, int out_size, void* d_ws, size_t ws_size,
                              hipStream_t stream) {
    const float* pon  = (const float*)d_in[0];
    const float* poff = (const float*)d_in[1];
    const float* ton  = (const float*)d_in[2];
    const float* toff = (const float*)d_in[3];
    float* ws = (float*)d_ws;   // 1024 blocks * 9 floats = 36 KB
    loss_partial<<<B_ROWS * SEG, BLK, 0, stream>>>(pon, poff, ton, toff, ws);
    finalize_k<<<1, BLK, 0, stream>>>(ws, (float*)d_out);
}

// Round 2
// 23.127 us; speedup vs baseline: 1.9782x; 1.9782x over previous
//
#include <hip/hip_runtime.h>
#include <math.h>

#define T_LEN 16384
#define B_ROWS 256
#define BLK 256
#define EPT 8                       // elements per thread
#define COLS (BLK * EPT)            // 2048 columns per block
#define SEG (T_LEN / COLS)          // 8 segments per row

#define LOG2E 1.44269504088896340f
#define LN2   0.69314718055994531f

// fast sigmoid: 1 v_exp + 1 v_rcp
__device__ __forceinline__ float fast_sig(float x) {
    float e = __builtin_amdgcn_exp2f(fabsf(x) * -LOG2E);
    float r = __builtin_amdgcn_rcpf(1.0f + e);
    return (x >= 0.f) ? r : e * r;
}

__global__ __launch_bounds__(BLK) void loss_partial(
    const float* __restrict__ pon, const float* __restrict__ poff,
    const float* __restrict__ ton, const float* __restrict__ toff,
    float* __restrict__ ws)
{
    const int blk = blockIdx.x;
    const int row = blk >> 3;            // SEG = 8
    const int s   = blk & 7;
    const int tid = threadIdx.x;
    const int C0  = s * COLS;            // segment start (row-local col)
    const int c0  = C0 + tid * EPT;      // this thread's first col
    const size_t rowbase = (size_t)row * T_LEN;

    __shared__ float on_h[BLK * 3];      // each thread's first 3 onset probs
    __shared__ float off_h[BLK * 3];     // each thread's first 3 offset probs
    __shared__ float part[4][9];

    float on_pos = 0.f, on_neg = 0.f, on_cnt = 0.f;
    float off_pos = 0.f, off_neg = 0.f, off_cnt = 0.f;
    float on_psum = 0.f, off_psum = 0.f, cons = 0.f;
    float w0 = 0.f, w1 = 0.f, w2 = 0.f;  // rolling window of last 3 onset probs

    const float4* pon4  = (const float4*)(pon  + rowbase + c0);
    const float4* poff4 = (const float4*)(poff + rowbase + c0);
    const float4* ton4  = (const float4*)(ton  + rowbase + c0);
    const float4* toff4 = (const float4*)(toff + rowbase + c0);

    #pragma unroll
    for (int k = 0; k < EPT / 4; k++) {
        float4 xo = pon4[k], xf = poff4[k], to = ton4[k], tf = toff4[k];
        float xs[4] = {xo.x, xo.y, xo.z, xo.w};
        float fs[4] = {xf.x, xf.y, xf.z, xf.w};
        float ts[4] = {to.x, to.y, to.z, to.w};
        float us[4] = {tf.x, tf.y, tf.z, tf.w};
        #pragma unroll
        for (int j = 0; j < 4; j++) {
            const int i = 4 * k + j;      // compile-time
            // ---- onset: BCE + prob (exp2/rcp/log2 hardware ops) ----
            float x  = xs[j];
            float e  = __builtin_amdgcn_exp2f(fabsf(x) * -LOG2E);
            float r  = __builtin_amdgcn_rcpf(1.0f + e);
            float l1pe = -LN2 * __builtin_amdgcn_logf(r);   // log(1+e)
            float l  = fmaxf(x, 0.f) + l1pe - x * ts[j];
            bool  tp = (ts[j] == 1.0f);
            on_pos += tp ? fminf(l, 5.0f) : 0.f;
            on_cnt += tp ? 1.0f : 0.f;
            on_neg += tp ? 0.f : l;
            float pr = (x >= 0.f) ? r : e * r;
            on_psum += pr;
            // ---- offset ----
            float y  = fs[j];
            float e2 = __builtin_amdgcn_exp2f(fabsf(y) * -LOG2E);
            float r2 = __builtin_amdgcn_rcpf(1.0f + e2);
            float l1pe2 = -LN2 * __builtin_amdgcn_logf(r2);
            float l2 = fmaxf(y, 0.f) + l1pe2 - y * us[j];
            bool  up = (us[j] == 1.0f);
            off_pos += up ? fminf(l2, 5.0f) : 0.f;
            off_cnt += up ? 1.0f : 0.f;
            off_neg += up ? 0.f : l2;
            float qr = (y >= 0.f) ? r2 : e2 * r2;
            off_psum += qr;
            // ---- halo stash (compile-time branch) ----
            if (i < 3) { on_h[tid * 3 + i] = pr; off_h[tid * 3 + i] = qr; }
            // ---- in-chunk violations: jg = c0+i-3, i>=3 ----
            if (i >= 3) {
                float rc = fmaxf(fmaxf(w0, w1), w2);
                cons += (rc > 0.5f && qr > 0.5f) ? rc * qr : 0.f;
            }
            w0 = w1; w1 = w2; w2 = pr;
        }
    }
    __syncthreads();

    // ---- tail violations: jg = c0+5, c0+6, c0+7 (need p8,p9,q8,q9,q10) ----
    {
        float p8, p9, q8, q9, q10;
        if (tid < BLK - 1) {
            int b = (tid + 1) * 3;
            p8 = on_h[b]; p9 = on_h[b + 1];
            q8 = off_h[b]; q9 = off_h[b + 1]; q10 = off_h[b + 2];
        } else {
            const float* onrow  = pon  + rowbase;
            const float* offrow = poff + rowbase;
            int h = C0 + COLS;
            p8  = (h     < T_LEN) ? fast_sig(onrow[h])      : 0.f;
            p9  = (h + 1 < T_LEN) ? fast_sig(onrow[h + 1])  : 0.f;
            q8  = (h     < T_LEN) ? fast_sig(offrow[h])     : 0.f;
            q9  = (h + 1 < T_LEN) ? fast_sig(offrow[h + 1]) : 0.f;
            q10 = (h + 2 < T_LEN) ? fast_sig(offrow[h + 2]) : 0.f;
        }
        // after the loop: w0=p5, w1=p6, w2=p7
        if (c0 + 5 <= T_LEN - 4) {
            float rc = fmaxf(fmaxf(w0, w1), w2);
            cons += (rc > 0.5f && q8 > 0.5f) ? rc * q8 : 0.f;
        }
        if (c0 + 6 <= T_LEN - 4) {
            float rc = fmaxf(fmaxf(w1, w2), p8);
            cons += (rc > 0.5f && q9 > 0.5f) ? rc * q9 : 0.f;
        }
        if (c0 + 7 <= T_LEN - 4) {
            float rc = fmaxf(fmaxf(w2, p8), p9);
            cons += (rc > 0.5f && q10 > 0.5f) ? rc * q10 : 0.f;
        }
    }

    // ---- block reduction: 9 partials ----
    float vals[9] = {on_pos, on_neg, on_cnt, off_pos, off_neg, off_cnt,
                     on_psum, off_psum, cons};
    #pragma unroll
    for (int v = 0; v < 9; v++) {
        float a = vals[v];
        for (int o = 32; o > 0; o >>= 1) a += __shfl_down(a, o, 64);
        vals[v] = a;
    }
    const int lane = tid & 63, wid = tid >> 6;
    if (lane == 0) {
        #pragma unroll
        for (int v = 0; v < 9; v++) part[wid][v] = vals[v];
    }
    __syncthreads();
    if (tid == 0) {
        float* o = ws + (size_t)blk * 9;
        #pragma unroll
        for (int v = 0; v < 9; v++)
            o[v] = part[0][v] + part[1][v] + part[2][v] + part[3][v];
    }
}

__global__ __launch_bounds__(256) void finalize_k(const float* __restrict__ ws,
                                                  float* __restrict__ out)
{
    int r = threadIdx.x;   // one row per thread
    double a[9];
    #pragma unroll
    for (int v = 0; v < 9; v++) a[v] = 0.0;
    for (int s = 0; s < SEG; s++) {
        const float* p = ws + ((size_t)r * SEG + s) * 9;
        #pragma unroll
        for (int v = 0; v < 9; v++) a[v] += (double)p[v];
    }
    double red[9];
    red[0] = a[0]; red[1] = a[1]; red[2] = a[2];
    red[3] = a[3]; red[4] = a[4]; red[5] = a[5];
    red[6] = a[6];
    red[7] = a[8];
    red[8] = fabs(a[6] - a[7]);          // per-row |sum_on - sum_off|
    #pragma unroll
    for (int v = 0; v < 9; v++) {
        double x = red[v];
        for (int o = 32; o > 0; o >>= 1) x += __shfl_down(x, o, 64);
        red[v] = x;
    }
    __shared__ double part[4][9];
    int lane = r & 63, wid = r >> 6;
    if (lane == 0) {
        #pragma unroll
        for (int v = 0; v < 9; v++) part[wid][v] = red[v];
    }
    __syncthreads();
    if (r == 0) {
        double t[9];
        #pragma unroll
        for (int v = 0; v < 9; v++)
            t[v] = part[0][v] + part[1][v] + part[2][v] + part[3][v];
        const double N = (double)B_ROWS * (double)T_LEN;
        double pc = t[2], nc = N - pc;
        double pl = (pc > 0) ? t[0] / fmax(pc, 1.0) : 0.0;
        double nl = (nc > 0) ? t[1] / fmax(nc, 1.0) : 0.0;
        double onset_loss = 1.5 * pl + nl;
        double pc2 = t[5], nc2 = N - pc2;
        double pl2 = (pc2 > 0) ? t[3] / fmax(pc2, 1.0) : 0.0;
        double nl2 = (nc2 > 0) ? t[4] / fmax(nc2, 1.0) : 0.0;
        double offset_loss = 1.5 * pl2 + nl2;
        double cons_loss = t[7] / ((double)B_ROWS * (double)(T_LEN - 3));
        double pair_loss = t[8] / (double)B_ROWS;
        double mean_on   = t[6] / N;
        double sparsity  = 0.0;   // SPARSE_W == 0
        double total = 5.0 * onset_loss + 3.0 * offset_loss + 0.1 * cons_loss
                     + 0.05 * pair_loss + sparsity;
        out[0] = (float)onset_loss;
        out[1] = (float)offset_loss;
        out[2] = (float)cons_loss;
        out[3] = (float)pair_loss;
        out[4] = (float)sparsity;
        out[5] = (float)mean_on;
        out[6] = (float)total;
    }
}

extern "C" void kernel_launch(void* const* d_in, const int* in_sizes, int n_in,
                              void* d_out, int out_size, void* d_ws, size_t ws_size,
                              hipStream_t stream) {
    const float* pon  = (const float*)d_in[0];
    const float* poff = (const float*)d_in[1];
    const float* ton  = (const float*)d_in[2];
    const float* toff = (const float*)d_in[3];
    float* ws = (float*)d_ws;   // 2048 blocks * 9 floats = 73.7 KB
    loss_partial<<<B_ROWS * SEG, BLK, 0, stream>>>(pon, poff, ton, toff, ws);
    finalize_k<<<1, BLK, 0, stream>>>(ws, (float*)d_out);
}